// Round 5
// baseline (288.447 us; speedup 1.0000x reference)
//
#include <hip/hip_runtime.h>
#include <stdint.h>

#define B_   32
#define CIN  64
#define COUT 64
#define H_   128
#define W_   128
#define WP   130
#define HW_  (H_ * W_)
#define SLOT (WP * 64)          // shorts per LDS row slot (16,640 B)

typedef __bf16 bf16x8 __attribute__((ext_vector_type(8)));
typedef float  f32x16 __attribute__((ext_vector_type(16)));

__device__ inline unsigned int f2bf(float f) {
  union { float f; unsigned u; } uf; uf.f = f;
  unsigned u = uf.u;
  unsigned r = 0x7FFFu + ((u >> 16) & 1u);
  return (u + r) >> 16;
}

// pack two floats -> one dword of 2x bf16 (v_cvt_pk_bf16_f32)
__device__ inline unsigned int pk2(float a, float b) {
  unsigned short x = __builtin_bit_cast(unsigned short, (__bf16)a);
  unsigned short y = __builtin_bit_cast(unsigned short, (__bf16)b);
  return (unsigned int)x | ((unsigned int)y << 16);
}

// Weights packed in 32x32x16 A-fragment order: one contiguous 1024B chunk per
// (b, p, ck16, ch) read as a single coalesced dwordx4 per wave.
// A[m][k]: m=cout=ch*32+(l&31), k=ci=ck16*16+(l>>5)*8+j.
// Wb index = ((((b*9+p)*4+ck16)*2+ch)*64 + l)*8 + j.
__global__ __launch_bounds__(256) void prep_w(const float* __restrict__ W0,
                                              const float* __restrict__ W1,
                                              const float* __restrict__ cov,
                                              unsigned short* __restrict__ Wb) {
  int g    = blockIdx.x * 256 + threadIdx.x;  // [0, 32*9*4096)
  int j    = g & 7;
  int l    = (g >> 3) & 63;
  int ch   = (g >> 9) & 1;
  int ck16 = (g >> 10) & 3;
  int v    = g >> 12;                         // b*9 + p
  int b    = v / 9;
  int p    = v - b * 9;
  int cout = ch * 32 + (l & 31);
  int ci   = ck16 * 16 + (l >> 5) * 8 + j;
  int widx = (cout * CIN + ci) * 9 + p;
  float val = W0[widx] + cov[b] * W1[widx];
  Wb[g] = (unsigned short)f2bf(val);
}

// Persistent strip conv: 256 blocks (1/CU) x 1024 threads (16 waves).
// Strip = 16 output rows, 8 steps of 2 rows. LDS = 6-slot input-row ring.
// Compute: one 32x32x16 MFMA tile per wave (32 cout x 32 px), 36 MFMA/step.
// B (pixels) from LDS (halved traffic vs 16x16), A (weights) from L2-hot
// global, coalesced 1024B per fragment -> A rides the TCC pipe, overlapping
// the LDS pipe. Single lgkm-only barrier per step (stores/loads in flight).
__global__ __launch_bounds__(1024, 4) void conv_strip(
    const float* __restrict__ X,
    const unsigned short* __restrict__ Wb,
    float* __restrict__ out) {
  __shared__ __align__(16) unsigned short Xs[6 * SLOT];  // 99,840 B

  // XCD swizzle: XCD (bid&7) owns batches 4x..4x+3 -> weight slice L2-hot
  int bid   = blockIdx.x;
  int b     = (bid & 7) * 4 + (bid >> 6);
  int strip = (bid >> 3) & 7;
  int h0    = strip * 16;

  int t  = threadIdx.x;
  int wv = t >> 6;                 // wave 0..15
  int l  = t & 63;

  // staging roles: a = row (0/1), o = ci octet (0..7)
  int a = wv >> 3;
  int o = wv & 7;
  // compute roles: ch = cout half, pq = pixel 32-block (0..7)
  int ch = wv & 1;
  int pq = wv >> 1;
  int rbase = pq >> 2;                       // row within step (0/1)
  int cpix  = (pq & 3) * 32 + (l & 31);      // pixel column (w' space base)
  int ohalf = l >> 5;                        // ci sub-octet select for B

  int wp0 = 2 * l + 1, wp1 = 2 * l + 2;      // staging pixel slots
  int sw0 = (o ^ (wp0 & 7)) << 3, sw1 = (o ^ (wp1 & 7)) << 3;

  // ---- prologue: halo columns + rows g=0..3 into slots 0..3 ----
  if (wv < 6) {
    unsigned int* d32 = (unsigned int*)(Xs + wv * SLOT + (l < 32 ? 0 : 129 * 64));
    d32[l & 31] = 0u;
  }
  {
    int r  = wv >> 2;                        // 0..3
    int ih = h0 - 1 + r;
    unsigned short* dr = Xs + r * SLOT;
    #pragma unroll
    for (int oi = 0; oi < 2; oi++) {
      int oo = (wv & 3) * 2 + oi;
      uint4 v0 = {0, 0, 0, 0}, v1 = {0, 0, 0, 0};
      if (ih >= 0) {
        const float* sp = X + ((size_t)(b * CIN + oo * 8) * H_ + ih) * W_ + 2 * l;
        float2 tt[8];
        #pragma unroll
        for (int j = 0; j < 8; j++) tt[j] = *(const float2*)(sp + (size_t)j * HW_);
        v0.x = pk2(tt[0].x, tt[1].x); v0.y = pk2(tt[2].x, tt[3].x);
        v0.z = pk2(tt[4].x, tt[5].x); v0.w = pk2(tt[6].x, tt[7].x);
        v1.x = pk2(tt[0].y, tt[1].y); v1.y = pk2(tt[2].y, tt[3].y);
        v1.z = pk2(tt[4].y, tt[5].y); v1.w = pk2(tt[6].y, tt[7].y);
      }
      *(uint4*)(dr + wp0 * 64 + ((oo ^ (wp0 & 7)) << 3)) = v0;
      *(uint4*)(dr + wp1 * 64 + ((oo ^ (wp1 & 7)) << 3)) = v1;
    }
  }
  __syncthreads();

  const unsigned short* wb9 = Wb + (size_t)b * 9 * 4096;

  float2 st[8];
  int sb = 0;                                // (2k) % 6

  #pragma unroll 1
  for (int k = 0; k < 8; k++) {
    // (1) convert + ds_write rows staged last step (g = 2k+2+a)
    if (k > 0) {
      int sw = sb + 2 + a; if (sw >= 6) sw -= 6;
      unsigned short* dr = Xs + sw * SLOT;
      uint4 v0, v1;
      v0.x = pk2(st[0].x, st[1].x); v0.y = pk2(st[2].x, st[3].x);
      v0.z = pk2(st[4].x, st[5].x); v0.w = pk2(st[6].x, st[7].x);
      v1.x = pk2(st[0].y, st[1].y); v1.y = pk2(st[2].y, st[3].y);
      v1.z = pk2(st[4].y, st[5].y); v1.w = pk2(st[6].y, st[7].y);
      *(uint4*)(dr + wp0 * 64 + sw0) = v0;
      *(uint4*)(dr + wp1 * 64 + sw1) = v1;
    }
    // (2) raw barrier: drain only LDS writes; global stores/loads stay in flight
    asm volatile("s_waitcnt lgkmcnt(0)" ::: "memory");
    __builtin_amdgcn_s_barrier();
    __builtin_amdgcn_sched_barrier(0);

    // (3) issue next rows' loads (g = 2k+4+a); consumed next step top
    if (k < 7) {
      int ih = h0 + 2 * k + 3 + a;
      if (ih <= 127) {
        const float* sp = X + ((size_t)(b * CIN + o * 8) * H_ + ih) * W_ + 2 * l;
        #pragma unroll
        for (int j = 0; j < 8; j++) st[j] = *(const float2*)(sp + (size_t)j * HW_);
      } else {
        #pragma unroll
        for (int j = 0; j < 8; j++) st[j] = (float2){0.f, 0.f};
      }
    }
    __builtin_amdgcn_sched_barrier(0);

    // (4) compute 9 taps from ring slots, 4 ck16 each: 36 x mfma 32x32x16
    f32x16 acc;
    #pragma unroll
    for (int i = 0; i < 16; i++) acc[i] = 0.f;

    #pragma unroll 1
    for (int kh = 0; kh < 3; kh++) {
      int r6 = sb + rbase + kh; if (r6 >= 6) r6 -= 6;
      const unsigned short* rp = Xs + r6 * SLOT;
      #pragma unroll
      for (int kw = 0; kw < 3; kw++) {
        const unsigned short* wk = wb9 + (size_t)((kh * 3 + kw) * 4 * 2 + ch) * 512;
        int c = cpix + kw;
        bf16x8 af[4], bfr[4];
        #pragma unroll
        for (int ck = 0; ck < 4; ck++)
          af[ck] = *(const bf16x8*)(wk + (size_t)ck * 1024 + l * 8);
        #pragma unroll
        for (int ck = 0; ck < 4; ck++) {
          int blk = (2 * ck + ohalf) ^ (c & 7);
          bfr[ck] = *(const bf16x8*)(rp + c * 64 + blk * 8);
        }
        __builtin_amdgcn_s_setprio(1);
        #pragma unroll
        for (int ck = 0; ck < 4; ck++)
          acc = __builtin_amdgcn_mfma_f32_32x32x16_bf16(af[ck], bfr[ck], acc, 0, 0, 0);
        __builtin_amdgcn_s_setprio(0);
      }
    }

    // (5) store this step's outputs: 32x32 C/D layout
    //     col=lane&31 (pixel), row=(reg&3)+8*(reg>>2)+4*(lane>>5) (cout)
    {
      int oh = h0 + 2 * k + rbase;
      size_t obase = (((size_t)b * COUT + ch * 32 + 4 * ohalf) * H_ + oh) * W_ + cpix;
      #pragma unroll
      for (int reg = 0; reg < 16; reg++) {
        int coff = (reg & 3) + 8 * (reg >> 2);
        out[obase + (size_t)coff * HW_] = acc[reg];
      }
    }

    sb += 2; if (sb >= 6) sb -= 6;
  }
}

extern "C" void kernel_launch(void* const* d_in, const int* in_sizes, int n_in,
                              void* d_out, int out_size, void* d_ws, size_t ws_size,
                              hipStream_t stream) {
  const float* x   = (const float*)d_in[0];
  const float* cov = (const float*)d_in[1];
  const float* W0  = (const float*)d_in[2];
  const float* W1  = (const float*)d_in[3];
  float* out = (float*)d_out;

  unsigned short* Wb = (unsigned short*)d_ws;   // 32*9*64*64*2 = 4,718,592 B

  prep_w    <<<dim3(4608), dim3(256),  0, stream>>>(W0, W1, cov, Wb);
  conv_strip<<<dim3(256),  dim3(1024), 0, stream>>>(x, Wb, out);
}